// Round 1
// 166.031 us; speedup vs baseline: 1.0075x; 1.0075x over previous
//
#include <hip/hip_runtime.h>
#include <math.h>
#include <limits.h>

#define NEG_INF -1e9f

// K1: s[e] = dot(edge_emb[e], W) -- one wave (64 lanes) per 256-float row.
// Memory-floor kernel: reads emb exactly once (102.4 MB), coalesced float4.
// Also zeroes the last-block ticket counter for K2 (ws is poisoned each iter).
__global__ __launch_bounds__(256) void k_edge_dot(
    const float* __restrict__ emb, const float* __restrict__ W,
    float* __restrict__ s, int* __restrict__ counter, int n_edges)
{
    if (blockIdx.x == 0 && threadIdx.x == 0) *counter = 0;
    int wave = (blockIdx.x * (int)blockDim.x + (int)threadIdx.x) >> 6;
    int lane = threadIdx.x & 63;
    if (wave >= n_edges) return;
    const float4 e = ((const float4*)emb)[wave * 64 + lane];
    const float4 w = ((const float4*)W)[lane];
    float d = e.x * w.x + e.y * w.y + e.z * w.z + e.w * w.w;
#pragma unroll
    for (int off = 32; off; off >>= 1) d += __shfl_down(d, off, 64);
    if (lane == 0) s[wave] = d;
}

// K2 (fused): per-path logit -> per-block softmax partials
// (max, first-index argmax, sum exp(l - blockmax)) -> last block combines
// partials, computes p / logprob, and materializes z[p].
// The logits array is never written: it was a pure intermediate.
__global__ __launch_bounds__(256) void k_fused(
    const float* __restrict__ s, const int* __restrict__ paths,
    const int* __restrict__ path_lens, const int* __restrict__ path_mask,
    const float* __restrict__ b, const float* __restrict__ emb,
    float* __restrict__ pmax, int* __restrict__ pidx, float* __restrict__ psum,
    int* __restrict__ counter, float* __restrict__ out,
    int n_paths, int max_len)
{
    __shared__ float rv[4];
    __shared__ int   ri[4];
    __shared__ float rs[4];
    __shared__ float s_bm, s_M, s_S;
    __shared__ int   s_bi, s_P, s_last;

    const int tid = threadIdx.x, lane = tid & 63, wv = tid >> 6;
    const int p = blockIdx.x * 256 + tid;

    // ---- per-path logit (mask short-circuit: no gathers for masked paths) ----
    float v = -INFINITY; int vi = INT_MAX;   // -inf sentinel for p >= n_paths
    if (p < n_paths) {
        vi = p;
        if (path_mask[p] == 0) {
            v = NEG_INF;
        } else {
            int len = path_lens[p] + 1;                 // 1..max_len
            float acc = 0.f;
            if (max_len == 16) {
                const int4* pp4 = (const int4*)(paths + (size_t)p * 16);
                int4 a0 = pp4[0], a1 = pp4[1], a2 = pp4[2], a3 = pp4[3];
                int idx[16] = { a0.x, a0.y, a0.z, a0.w, a1.x, a1.y, a1.z, a1.w,
                                a2.x, a2.y, a2.z, a2.w, a3.x, a3.y, a3.z, a3.w };
#pragma unroll
                for (int j = 0; j < 16; ++j) {
                    float t = s[idx[j]];                // always in-bounds
                    acc += (j < len) ? t : 0.f;
                }
            } else {
                const int* pp = paths + (size_t)p * max_len;
                for (int j = 0; j < len; ++j) acc += s[pp[j]];
            }
            v = acc / (float)len + b[0];
        }
    }

    // ---- block max + argmax (first-occurrence tie-break) ----
    float bv = v; int bi = vi;
#pragma unroll
    for (int off = 32; off; off >>= 1) {
        float ov = __shfl_down(bv, off, 64);
        int   oi = __shfl_down(bi, off, 64);
        if (ov > bv || (ov == bv && oi < bi)) { bv = ov; bi = oi; }
    }
    if (lane == 0) { rv[wv] = bv; ri[wv] = bi; }
    __syncthreads();
    if (tid == 0) {
        float mv = rv[0]; int mi = ri[0];
        for (int w = 1; w < 4; ++w)
            if (rv[w] > mv || (rv[w] == mv && ri[w] < mi)) { mv = rv[w]; mi = ri[w]; }
        s_bm = mv; s_bi = mi;
    }
    __syncthreads();
    const float bm = s_bm;      // >= NEG_INF: every block has >= 1 valid path

    // ---- block sum of exp(v - bm); exp(-inf)=0 handles inactive lanes ----
    float se = expf(v - bm);
#pragma unroll
    for (int off = 32; off; off >>= 1) se += __shfl_down(se, off, 64);
    if (lane == 0) rs[wv] = se;
    __syncthreads();

    // ---- publish partials; last block elects itself via device-scope ticket ----
    if (tid == 0) {
        pmax[blockIdx.x] = bm;
        pidx[blockIdx.x] = s_bi;
        psum[blockIdx.x] = rs[0] + rs[1] + rs[2] + rs[3];
        __threadfence();                        // release partials (device scope)
        int tk = atomicAdd(counter, 1);         // device-scope RMW
        s_last = (tk == (int)gridDim.x - 1) ? 1 : 0;
    }
    __syncthreads();
    if (!s_last) return;
    __threadfence();                            // acquire all blocks' partials

    // ---- combine: global max + argmax over nb partials ----
    const int nb = gridDim.x;
    float mv = -INFINITY; int mi = INT_MAX;
    for (int i = tid; i < nb; i += 256) {
        float t = pmax[i]; int ti = pidx[i];
        if (t > mv || (t == mv && ti < mi)) { mv = t; mi = ti; }
    }
#pragma unroll
    for (int off = 32; off; off >>= 1) {
        float ov = __shfl_down(mv, off, 64);
        int   oi = __shfl_down(mi, off, 64);
        if (ov > mv || (ov == mv && oi < mi)) { mv = ov; mi = oi; }
    }
    if (lane == 0) { rv[wv] = mv; ri[wv] = mi; }
    __syncthreads();
    if (tid == 0) {
        float M = rv[0]; int P = ri[0];
        for (int w = 1; w < 4; ++w)
            if (rv[w] > M || (rv[w] == M && ri[w] < P)) { M = rv[w]; P = ri[w]; }
        s_M = M; s_P = P;
    }
    __syncthreads();
    const float M = s_M; const int P = s_P;

    // ---- S = sum_b psum[b] * exp(pmax[b] - M); logprob = -log(S) ----
    // all-masked blocks: exp(-1e9 - M) underflows to 0 -> contribution 0,
    // matching exp(-1e9 - M) == 0 per masked path in the reference.
    float sp = 0.f;
    for (int i = tid; i < nb; i += 256)
        sp += psum[i] * expf(pmax[i] - M);
#pragma unroll
    for (int off = 32; off; off >>= 1) sp += __shfl_down(sp, off, 64);
    if (lane == 0) rs[wv] = sp;
    __syncthreads();
    if (tid == 0) s_S = rs[0] + rs[1] + rs[2] + rs[3];
    __syncthreads();

    // ---- z[P]: 256 threads, one per hidden dim ----
    const int lenP = path_lens[P] + 1;
    const int* pp = paths + (size_t)P * max_len;
    float acc = 0.f;
    for (int j = 0; j < lenP; ++j)
        acc += emb[(size_t)pp[j] * 256 + tid];
    out[2 + tid] = acc / (float)lenP;
    if (tid == 0) { out[0] = (float)P; out[1] = -logf(s_S); }  // l_P == M exactly
}

extern "C" void kernel_launch(void* const* d_in, const int* in_sizes, int n_in,
                              void* d_out, int out_size, void* d_ws, size_t ws_size,
                              hipStream_t stream) {
    const float* emb       = (const float*)d_in[0];   // [n_edges, 256]
    const int*   paths     = (const int*)  d_in[1];   // [n_paths, max_len]
    const int*   path_lens = (const int*)  d_in[2];   // [n_paths]
    const int*   path_mask = (const int*)  d_in[3];   // [n_paths]
    const float* W         = (const float*)d_in[4];   // [256]
    const float* b         = (const float*)d_in[5];   // [1]

    int hidden  = in_sizes[4];                 // 256
    int n_edges = in_sizes[0] / hidden;        // 100000
    int n_paths = in_sizes[2];                 // 20000
    int max_len = in_sizes[1] / n_paths;       // 16

    int blocks2 = (n_paths + 255) / 256;       // 79

    // workspace layout
    float* s       = (float*)d_ws;             // [n_edges]
    float* pmax    = s + n_edges;              // [blocks2]
    float* psum    = pmax + blocks2;           // [blocks2]
    int*   pidx    = (int*)(psum + blocks2);   // [blocks2]
    int*   counter = pidx + blocks2;           // [1]

    // K1: one wave per edge row -> 4 waves/block (also zeroes counter)
    int blocks1 = (n_edges * 64 + 255) / 256;
    k_edge_dot<<<blocks1, 256, 0, stream>>>(emb, W, s, counter, n_edges);

    // K2: per-path logits + fused softmax reduction + final outputs
    k_fused<<<blocks2, 256, 0, stream>>>(s, paths, path_lens, path_mask, b, emb,
                                         pmax, pidx, psum, counter,
                                         (float*)d_out, n_paths, max_len);
}